// Round 3
// baseline (925.732 us; speedup 1.0000x reference)
//
#include <hip/hip_runtime.h>
#include <cstdint>
#include <cstddef>

// ---------------------------------------------------------------------------
// SpatialGRU 32x32, B=64, U=64, C=64. Persistent: 32 rows x 4 batch-tiles.
// R3: (1) XCD-affinity bid remap (rows 0-15 of a bt on one XCD, 16-31 on
// another -> cross-row handoff stays in one L2); (2) sigmoid fused into
// GEMM1's r-waves (one fewer sync, no Gs round-trip for r); (3) GEMM2
// k-split across all 8 waves + LDS fp32 atomic reduction (no single-wave
// serial phase). 4 syncthreads per cell.
// ---------------------------------------------------------------------------

#define LDIM   32
#define BATCH  64
#define UNITS  64
#define CHAN   64
#define NBT    4
#define BT     16
#define TPB    512

typedef _Float16 f16;
typedef _Float16 f16x8 __attribute__((ext_vector_type(8)));
typedef float    f32x4 __attribute__((ext_vector_type(4)));

__global__ __launch_bounds__(TPB) void zero_flags_kernel(int* __restrict__ f) {
    int i = blockIdx.x * TPB + threadIdx.x;
    if (i < LDIM * LDIM * NBT) f[i] = 0;
}

__global__ __launch_bounds__(TPB, 2) void spatial_gru_kernel(
    const float* __restrict__ x,     // (B, C, 32, 32)
    const float* __restrict__ W,     // (256, 448)
    const float* __restrict__ Urec,  // (192, 64)
    const float* __restrict__ bias,  // (512,)
    const float* __restrict__ Wij,   // (64, 64)
    float* __restrict__ out,         // (B, U)
    int* __restrict__ flags,
    float* __restrict__ states)      // (32, 32, B, U)
{
    const int bid = blockIdx.x;
    // XCD-affinity remap: bid = bt + 4*(row/16) + 8*(row%16)
    // -> XCD(bid%8) constant for rows 0..15 (=bt) and rows 16..31 (=bt+4).
    const int bt  = bid & 3;
    const int row = ((bid >> 2) & 1) * 16 + (bid >> 3);
    const int b0  = bt * BT;
    const int t   = (int)threadIdx.x;
    const int u   = t & 63;
    const int g   = t >> 6;          // wave id 0..7 (uniform); also batch idx base
    const int l15 = t & 15;          // MFMA n-col / A-row lane
    const int lq  = (t & 63) >> 4;   // MFMA k-quad / C-row quad

    // ---- LDS ----
    // qf  : GEMM1 A (f16)  [b][k]  k: 0:64 hT | 64:128 hL | 128:192 hD | 192:256 s
    // rf  : GEMM2 A (f16)  [b][k]  k: 0:192 r*{hL,hT,hD} | 192:256 s
    // qs32: fp32 state     [b][c]  c: 0:64 hT | 64:128 hL | 128:192 hD
    // Gsz : z logits fp32  [b][n]  n: 0:256 (= W cols 192:448)
    // pacc: GEMM2 partial  [b][n]  fp32, reduced via LDS atomics
    __shared__ __attribute__((aligned(16))) f16 qf[BT][264];
    __shared__ __attribute__((aligned(16))) f16 rf[BT][264];
    __shared__ float qs32[BT][204];
    __shared__ float Gsz [BT][260];
    __shared__ float pacc[BT][68];

    // ---- GEMM1 weights resident in registers (waves 0..6: 64 cols each) ----
    f16x8 wreg[4][8];
    float bias1[4] = {0.f, 0.f, 0.f, 0.f};
    if (g < 7) {
        const int nb = g * 64 + l15;
#pragma unroll
        for (int T = 0; T < 4; ++T) {
            bias1[T] = bias[nb + 16 * T];
#pragma unroll
            for (int s = 0; s < 8; ++s) {
                f16x8 v;
#pragma unroll
                for (int jj = 0; jj < 8; ++jj) {
                    int kk = s * 32 + lq * 8 + jj;
                    v[jj] = (f16)W[(size_t)kk * 448 + nb + 16 * T];
                }
                wreg[T][s] = v;
            }
        }
    }
    // ---- GEMM2 weights: every wave holds k-chunk [32g, 32g+32) of [Urec;Wij]
    f16x8 wreg2[4];
#pragma unroll
    for (int T = 0; T < 4; ++T) {
        const int nn = T * 16 + l15;
        f16x8 v;
#pragma unroll
        for (int jj = 0; jj < 8; ++jj) {
            int kk = g * 32 + lq * 8 + jj;
            float wv = (kk < 192) ? Urec[kk * 64 + nn] : Wij[(kk - 192) * 64 + nn];
            v[jj] = (f16)wv;
        }
        wreg2[T] = v;
    }
    const float bij = bias[448 + u];

    // ---- zero initial state ----
    for (int idx = t; idx < 192 * BT; idx += TPB) {
        int b = idx & 15, k = idx >> 4;
        qs32[b][k] = 0.f;
        qf[b][k] = (f16)0.f;
    }
    __syncthreads();

    // x prefetch (this thread: channel u, batches b0+g and b0+g+8)
    const size_t xb0 = (size_t)(b0 + g) * 65536 + (size_t)u * 1024 + (size_t)row * 32;
    const size_t xb1 = xb0 + (size_t)8 * 65536;
    float x0 = x[xb0], x1 = x[xb1];

    for (int j = 0; j < LDIM; ++j) {
        // ---- [A] stage x; wait for (row-1,j); stage h_top ----
        qf[g][192 + u]     = (f16)x0;  rf[g][192 + u]     = (f16)x0;
        qf[g + 8][192 + u] = (f16)x1;  rf[g + 8][192 + u] = (f16)x1;
        float ht0 = 0.f, ht1 = 0.f;
        if (row > 0) {
            const int* fl = flags + ((row - 1) * LDIM + j) * NBT + bt;
            while (__hip_atomic_load(fl, __ATOMIC_RELAXED, __HIP_MEMORY_SCOPE_AGENT) == 0) {
                __builtin_amdgcn_s_sleep(1);
            }
            asm volatile("" ::: "memory");
            const float* sp = states + (((size_t)(row - 1) * LDIM + j) * BATCH + b0) * UNITS;
            ht0 = __hip_atomic_load(sp + (size_t)g * 64 + u,
                                    __ATOMIC_RELAXED, __HIP_MEMORY_SCOPE_AGENT);
            ht1 = __hip_atomic_load(sp + (size_t)(g + 8) * 64 + u,
                                    __ATOMIC_RELAXED, __HIP_MEMORY_SCOPE_AGENT);
        }
        qs32[g][u]     = ht0;  qf[g][u]     = (f16)ht0;
        qs32[g + 8][u] = ht1;  qf[g + 8][u] = (f16)ht1;
        __syncthreads();   // s1

        // prefetch next cell's x (overlaps GEMM1)
        float nx0 = 0.f, nx1 = 0.f;
        if (j < LDIM - 1) { nx0 = x[xb0 + j + 1]; nx1 = x[xb1 + j + 1]; }

        // ---- [C'] GEMM1 (waves 0..6) + fused sigmoid (waves 0..2);
        //      wave 7 zeroes pacc ----
        if (g < 7) {
            f32x4 acc[4];
#pragma unroll
            for (int T = 0; T < 4; ++T)
                acc[T] = (f32x4){bias1[T], bias1[T], bias1[T], bias1[T]};
#pragma unroll
            for (int s = 0; s < 8; ++s) {
                f16x8 a = *(const f16x8*)&qf[l15][s * 32 + lq * 8];
#pragma unroll
                for (int T = 0; T < 4; ++T)
                    acc[T] = __builtin_amdgcn_mfma_f32_16x16x32_f16(a, wreg[T][s], acc[T], 0, 0, 0);
            }
            if (g < 3) {
                // r-cols: k = g*64 + T*16 + l15 in 0:192
                // h_sel col: k<64 -> hL(64+k) ; 64<=k<128 -> hT(k-64) ; else hD(k)
                const int colbase = (g == 0) ? 64 : (g == 1) ? 0 : 128;
#pragma unroll
                for (int T = 0; T < 4; ++T)
#pragma unroll
                    for (int r = 0; r < 4; ++r) {
                        float rr = 1.f / (1.f + __expf(-acc[T][r]));
                        int b = lq * 4 + r;
                        float hv = qs32[b][colbase + T * 16 + l15];
                        rf[b][g * 64 + T * 16 + l15] = (f16)(rr * hv);
                    }
            } else {
                const int zb = (g - 3) * 64;
#pragma unroll
                for (int T = 0; T < 4; ++T)
#pragma unroll
                    for (int r = 0; r < 4; ++r)
                        Gsz[lq * 4 + r][zb + T * 16 + l15] = acc[T][r];
            }
        } else {
            float* pf = &pacc[0][0];
            for (int i = u; i < BT * 68; i += 64) pf[i] = 0.f;
        }
        __syncthreads();   // s2

        // ---- [E'] GEMM2 k-split: wave g does k in [32g, 32g+32) ----
        {
            f16x8 a = *(const f16x8*)&rf[l15][g * 32 + lq * 8];
            f32x4 z4 = (f32x4){0.f, 0.f, 0.f, 0.f};
#pragma unroll
            for (int T = 0; T < 4; ++T) {
                f32x4 pa = __builtin_amdgcn_mfma_f32_16x16x32_f16(a, wreg2[T], z4, 0, 0, 0);
#pragma unroll
                for (int r = 0; r < 4; ++r)
                    atomicAdd(&pacc[lq * 4 + r][T * 16 + l15], pa[r]);
            }
        }
        __syncthreads();   // s3

        // ---- [F'] tanh + softmax gates + combine + store + rotate ----
#pragma unroll
        for (int i = 0; i < 2; ++i) {
            int b = g + 8 * i;
            float hhv = bij + pacc[b][u];
            float e2 = __expf(2.f * hhv);
            float th = 1.f - 2.f / (e2 + 1.f);          // tanh
            float zi = Gsz[b][u],       zl = Gsz[b][64 + u];
            float zt = Gsz[b][128 + u], zd = Gsz[b][192 + u];
            float mx = fmaxf(fmaxf(zi, zl), fmaxf(zt, zd));
            float ei = __expf(zi - mx), el = __expf(zl - mx);
            float et = __expf(zt - mx), ed = __expf(zd - mx);
            float inv = 1.f / (ei + el + et + ed);
            float hT = qs32[b][u], hL = qs32[b][64 + u], hD = qs32[b][128 + u];
            float hv = (el * hL + et * hT + ed * hD + ei * th) * inv;

            __hip_atomic_store(
                states + (((size_t)row * LDIM + j) * BATCH + b0 + b) * UNITS + u,
                hv, __ATOMIC_RELAXED, __HIP_MEMORY_SCOPE_AGENT);
            if (row == LDIM - 1 && j == LDIM - 1)
                out[(size_t)(b0 + b) * UNITS + u] = hv;

            // rotate (this thread owns slots (b,u)): hD <- hT, hL <- h_new
            qs32[b][128 + u] = hT;
            qs32[b][64 + u]  = hv;
            f16 htf = qf[b][u];
            qf[b][128 + u] = htf;
            qf[b][64 + u]  = (f16)hv;
        }
        asm volatile("s_waitcnt vmcnt(0)" ::: "memory");
        __syncthreads();   // s4 — state stores drained, rotations done
        if (t == 0) {
            __hip_atomic_store(flags + (row * LDIM + j) * NBT + bt, 1,
                               __ATOMIC_RELAXED, __HIP_MEMORY_SCOPE_AGENT);
        }
        x0 = nx0; x1 = nx1;
    }
}

extern "C" void kernel_launch(void* const* d_in, const int* in_sizes, int n_in,
                              void* d_out, int out_size, void* d_ws, size_t ws_size,
                              hipStream_t stream) {
    const float* x    = (const float*)d_in[0];
    const float* W    = (const float*)d_in[1];
    const float* Urec = (const float*)d_in[2];
    const float* bias = (const float*)d_in[3];
    const float* Wij  = (const float*)d_in[4];
    float* out = (float*)d_out;

    int*   flags  = (int*)d_ws;
    float* states = (float*)((char*)d_ws + 16384);

    int nflags = LDIM * LDIM * NBT;
    zero_flags_kernel<<<(nflags + TPB - 1) / TPB, TPB, 0, stream>>>(flags);

    spatial_gru_kernel<<<LDIM * NBT, TPB, 0, stream>>>(
        x, W, Urec, bias, Wij, out, flags, states);
}

// Round 4
// 279.994 us; speedup vs baseline: 3.3063x; 3.3063x over previous
//
#include <hip/hip_runtime.h>
#include <cstdint>
#include <cstddef>

// ---------------------------------------------------------------------------
// SpatialGRU 32x32, B=64, U=64, C=64. Persistent: 32 rows x 4 batch-tiles
// (bid = row*4+bt, the R2-proven mapping). Cross-row h via global states +
// PER-WAVE flags (agent scope, cache-bypass -> XCD-safe).
// R4: fused sigmoid in GEMM1 r-waves; GEMM2 k-split over waves 4-7 into 4
// private LDS buffers (NO fp32 LDS atomics - they lower to CAS loops);
// per-wave drain+flag (no tail barrier). 3 syncthreads per cell.
// ---------------------------------------------------------------------------

#define LDIM   32
#define BATCH  64
#define UNITS  64
#define CHAN   64
#define NBT    4
#define BT     16
#define TPB    512
#define NFLAGS (LDIM * LDIM * NBT * 8)     // per-cell, per-bt, per-wave

typedef _Float16 f16;
typedef _Float16 f16x8 __attribute__((ext_vector_type(8)));
typedef float    f32x4 __attribute__((ext_vector_type(4)));

__global__ __launch_bounds__(TPB) void zero_flags_kernel(int* __restrict__ f) {
    int i = blockIdx.x * TPB + threadIdx.x;
    if (i < NFLAGS) f[i] = 0;
}

__global__ __launch_bounds__(TPB, 2) void spatial_gru_kernel(
    const float* __restrict__ x,     // (B, C, 32, 32)
    const float* __restrict__ W,     // (256, 448)
    const float* __restrict__ Urec,  // (192, 64)
    const float* __restrict__ bias,  // (512,)
    const float* __restrict__ Wij,   // (64, 64)
    float* __restrict__ out,         // (B, U)
    int* __restrict__ flags,
    float* __restrict__ states)      // (32, 32, B, U)
{
    const int bid = blockIdx.x;
    const int row = bid >> 2;        // R2-proven mapping
    const int bt  = bid & 3;
    const int b0  = bt * BT;
    const int t   = (int)threadIdx.x;
    const int u   = t & 63;
    const int g   = t >> 6;          // wave id 0..7 (uniform); also batch base
    const int l15 = t & 15;          // MFMA n-col / A-row lane
    const int lq  = (t & 63) >> 4;   // MFMA k-quad / C-row quad

    // ---- LDS ----
    // qf  : GEMM1 A (f16)  [b][k]  k: 0:64 hT | 64:128 hL | 128:192 hD | 192:256 s
    // rf  : GEMM2 A (f16)  [b][k]  k: 0:192 r*{hL,hT,hD} | 192:256 s
    // qs32: fp32 state     [b][c]  c: 0:64 hT | 64:128 hL | 128:192 hD
    // Gsz : z logits fp32  [b][n]  n: 0:256 (= W cols 192:448)
    // pacc: GEMM2 partials [w][b][n]  (wave w+4 writes slice w; plain stores)
    __shared__ __attribute__((aligned(16))) f16 qf[BT][264];
    __shared__ __attribute__((aligned(16))) f16 rf[BT][264];
    __shared__ float qs32[BT][204];
    __shared__ float Gsz [BT][260];
    __shared__ float pacc[4][BT][68];

    // ---- GEMM1 weights resident in registers (waves 0..6: 64 cols each) ----
    f16x8 wreg[4][8];
    float bias1[4] = {0.f, 0.f, 0.f, 0.f};
    if (g < 7) {
        const int nb = g * 64 + l15;
#pragma unroll
        for (int T = 0; T < 4; ++T) {
            bias1[T] = bias[nb + 16 * T];
#pragma unroll
            for (int s = 0; s < 8; ++s) {
                f16x8 v;
#pragma unroll
                for (int jj = 0; jj < 8; ++jj) {
                    int kk = s * 32 + lq * 8 + jj;
                    v[jj] = (f16)W[(size_t)kk * 448 + nb + 16 * T];
                }
                wreg[T][s] = v;
            }
        }
    }
    // ---- GEMM2 weights: waves 4..7 hold k-chunk [(g-4)*64, (g-4)*64+64) ----
    f16x8 wreg2[4][2];
    {
        const int kb = (g & 3) * 64;     // waves 4..7 use (g-4)*64 == (g&3)*64
#pragma unroll
        for (int T = 0; T < 4; ++T) {
            const int nn = T * 16 + l15;
#pragma unroll
            for (int s = 0; s < 2; ++s) {
                f16x8 v;
#pragma unroll
                for (int jj = 0; jj < 8; ++jj) {
                    int kk = kb + s * 32 + lq * 8 + jj;
                    float wv = (kk < 192) ? Urec[kk * 64 + nn] : Wij[(kk - 192) * 64 + nn];
                    v[jj] = (f16)wv;
                }
                wreg2[T][s] = v;
            }
        }
    }
    const float bij = bias[448 + u];

    // ---- zero initial state ----
    for (int idx = t; idx < 192 * BT; idx += TPB) {
        int b = idx & 15, k = idx >> 4;
        qs32[b][k] = 0.f;
        qf[b][k] = (f16)0.f;
    }
    __syncthreads();

    // x: this thread handles channel u, batches b0+g and b0+g+8
    const size_t xb0 = (size_t)(b0 + g) * 65536 + (size_t)u * 1024 + (size_t)row * 32;
    const size_t xb1 = xb0 + (size_t)8 * 65536;
    float x0 = x[xb0], x1 = x[xb1];

    for (int j = 0; j < LDIM; ++j) {
        // ---- [A] stage x; per-wave wait for (row-1,j); stage h_top ----
        qf[g][192 + u]     = (f16)x0;  rf[g][192 + u]     = (f16)x0;
        qf[g + 8][192 + u] = (f16)x1;  rf[g + 8][192 + u] = (f16)x1;
        float ht0 = 0.f, ht1 = 0.f;
        if (row > 0) {
            // wave g polls ITS producer wave's flag (producer wave g wrote
            // exactly batches g and g+8)
            const int* fl = flags + (((row - 1) * LDIM + j) * NBT + bt) * 8 + g;
            while (__hip_atomic_load(fl, __ATOMIC_RELAXED, __HIP_MEMORY_SCOPE_AGENT) == 0) {
                __builtin_amdgcn_s_sleep(1);
            }
            asm volatile("" ::: "memory");
            const float* sp = states + (((size_t)(row - 1) * LDIM + j) * BATCH + b0) * UNITS;
            ht0 = __hip_atomic_load(sp + (size_t)g * 64 + u,
                                    __ATOMIC_RELAXED, __HIP_MEMORY_SCOPE_AGENT);
            ht1 = __hip_atomic_load(sp + (size_t)(g + 8) * 64 + u,
                                    __ATOMIC_RELAXED, __HIP_MEMORY_SCOPE_AGENT);
        }
        qs32[g][u]     = ht0;  qf[g][u]     = (f16)ht0;
        qs32[g + 8][u] = ht1;  qf[g + 8][u] = (f16)ht1;
        __syncthreads();   // s1

        // prefetch next cell's x (overlaps GEMM1)
        float nx0 = 0.f, nx1 = 0.f;
        if (j < LDIM - 1) { nx0 = x[xb0 + j + 1]; nx1 = x[xb1 + j + 1]; }

        // ---- [C] GEMM1 (waves 0..6) + fused sigmoid on r-waves 0..2 ----
        if (g < 7) {
            f32x4 acc[4];
#pragma unroll
            for (int T = 0; T < 4; ++T)
                acc[T] = (f32x4){bias1[T], bias1[T], bias1[T], bias1[T]};
#pragma unroll
            for (int s = 0; s < 8; ++s) {
                f16x8 a = *(const f16x8*)&qf[l15][s * 32 + lq * 8];
#pragma unroll
                for (int T = 0; T < 4; ++T)
                    acc[T] = __builtin_amdgcn_mfma_f32_16x16x32_f16(a, wreg[T][s], acc[T], 0, 0, 0);
            }
            if (g < 3) {
                // k = g*64+T*16+l15: g=0 -> r*hL (qs32 col 64+k), g=1 -> r*hT
                // (col k-64), g=2 -> r*hD (col k)   [matches ref concat order]
                const int colbase = (g == 0) ? 64 : (g == 1) ? 0 : 128;
#pragma unroll
                for (int T = 0; T < 4; ++T)
#pragma unroll
                    for (int r = 0; r < 4; ++r) {
                        float rr = 1.f / (1.f + __expf(-acc[T][r]));
                        int b = lq * 4 + r;
                        float hv = qs32[b][colbase + T * 16 + l15];
                        rf[b][g * 64 + T * 16 + l15] = (f16)(rr * hv);
                    }
            } else {
                const int zb = (g - 3) * 64;
#pragma unroll
                for (int T = 0; T < 4; ++T)
#pragma unroll
                    for (int r = 0; r < 4; ++r)
                        Gsz[lq * 4 + r][zb + T * 16 + l15] = acc[T][r];
            }
        }
        __syncthreads();   // s2

        // ---- [E] GEMM2 k-split: waves 4..7, k-chunk (g-4)*64, private pacc ----
        if (g >= 4) {
            const int w  = g - 4;
            const int kb = w * 64;
            f32x4 acc[4];
#pragma unroll
            for (int T = 0; T < 4; ++T) acc[T] = (f32x4){0.f, 0.f, 0.f, 0.f};
#pragma unroll
            for (int s = 0; s < 2; ++s) {
                f16x8 a = *(const f16x8*)&rf[l15][kb + s * 32 + lq * 8];
#pragma unroll
                for (int T = 0; T < 4; ++T)
                    acc[T] = __builtin_amdgcn_mfma_f32_16x16x32_f16(a, wreg2[T][s], acc[T], 0, 0, 0);
            }
#pragma unroll
            for (int T = 0; T < 4; ++T)
#pragma unroll
                for (int r = 0; r < 4; ++r)
                    pacc[w][lq * 4 + r][T * 16 + l15] = acc[T][r];
        }
        __syncthreads();   // s3

        // ---- [F] tanh + softmax gates + combine + store + rotate ----
        // (touches only this thread's LDS slots -> no barrier after)
#pragma unroll
        for (int i = 0; i < 2; ++i) {
            int b = g + 8 * i;
            float hhv = bij + pacc[0][b][u] + pacc[1][b][u] + pacc[2][b][u] + pacc[3][b][u];
            float e2 = __expf(2.f * hhv);
            float th = 1.f - 2.f / (e2 + 1.f);          // tanh
            float zi = Gsz[b][u],       zl = Gsz[b][64 + u];
            float zt = Gsz[b][128 + u], zd = Gsz[b][192 + u];
            float mx = fmaxf(fmaxf(zi, zl), fmaxf(zt, zd));
            float ei = __expf(zi - mx), el = __expf(zl - mx);
            float et = __expf(zt - mx), ed = __expf(zd - mx);
            float inv = 1.f / (ei + el + et + ed);
            float hT = qs32[b][u], hL = qs32[b][64 + u], hD = qs32[b][128 + u];
            float hv = (el * hL + et * hT + ed * hD + ei * th) * inv;

            __hip_atomic_store(
                states + (((size_t)row * LDIM + j) * BATCH + b0 + b) * UNITS + u,
                hv, __ATOMIC_RELAXED, __HIP_MEMORY_SCOPE_AGENT);
            if (row == LDIM - 1 && j == LDIM - 1)
                out[(size_t)(b0 + b) * UNITS + u] = hv;

            // rotate own slots: hD <- hT, hL <- h_new
            qs32[b][128 + u] = hT;
            qs32[b][64 + u]  = hv;
            f16 htf = qf[b][u];
            qf[b][128 + u] = htf;
            qf[b][64 + u]  = (f16)hv;
        }
        // per-WAVE drain of this wave's 128 state stores, then per-wave flag
        asm volatile("s_waitcnt vmcnt(0)" ::: "memory");
        if (u == 0) {
            __hip_atomic_store(flags + ((row * LDIM + j) * NBT + bt) * 8 + g, 1,
                               __ATOMIC_RELAXED, __HIP_MEMORY_SCOPE_AGENT);
        }
        x0 = nx0; x1 = nx1;
        // no tail barrier: [A] writes only thread-owned slots; s1 covers the rest
    }
}

extern "C" void kernel_launch(void* const* d_in, const int* in_sizes, int n_in,
                              void* d_out, int out_size, void* d_ws, size_t ws_size,
                              hipStream_t stream) {
    const float* x    = (const float*)d_in[0];
    const float* W    = (const float*)d_in[1];
    const float* Urec = (const float*)d_in[2];
    const float* bias = (const float*)d_in[3];
    const float* Wij  = (const float*)d_in[4];
    float* out = (float*)d_out;

    int*   flags  = (int*)d_ws;
    float* states = (float*)((char*)d_ws + 131072);

    zero_flags_kernel<<<(NFLAGS + TPB - 1) / TPB, TPB, 0, stream>>>(flags);

    spatial_gru_kernel<<<LDIM * NBT, TPB, 0, stream>>>(
        x, W, Urec, bias, Wij, out, flags, states);
}